// Round 9
// baseline (4157.753 us; speedup 1.0000x reference)
//
#include <hip/hip_runtime.h>

#define BATCH 512
#define SEQL  512
#define NIN   128
#define NH    512
#define NOUT  128
#define PRED  32
#define NSTEP (SEQL + PRED)

#define G_B 8
#define G_H 16
#define BT  64
#define UW  32              // hidden units per WG
#define NWG (G_B * G_H)     // 128
#define NTHREADS 256

// LDS layout (shorts), all weights in MFMA-FRAGMENT order:
// frag f base = f*512 + lane*8 -> ds_read_b128 perfectly linear per
// instruction, ZERO bank conflicts, no index math.
// Whh: 6 (gate,unit-tile) x 16 ks = 96 frags; Wih: 6 x 4 = 24; Wout: 16.
#define OFF_WIH   49152     // 96*512
#define OFF_WOUT  61440     // + 24*512
#define OFF_TR    69632     // + 16*512
#define LDS_SHORTS 71936    // + 4 waves * 16*36 transpose scratch
#define LDS_BYTES (LDS_SHORTS * 2)

typedef short bf16x8 __attribute__((ext_vector_type(8)));
typedef float f32x4 __attribute__((ext_vector_type(4)));
typedef unsigned int u32x4 __attribute__((ext_vector_type(4)));

#define MFMA __builtin_amdgcn_mfma_f32_16x16x32_bf16

__device__ __forceinline__ unsigned short f2bf(float f) {
    unsigned int u = __float_as_uint(f);
    u = (u + 0x7fffu + ((u >> 16) & 1u)) >> 16;   // RTNE
    return (unsigned short)u;
}
__device__ __forceinline__ float sigm(float x) {
    x = fminf(fmaxf(x, -30.f), 30.f);
    return 1.f / (1.f + __expf(-x));
}
__device__ __forceinline__ float tanh_f(float x) {
    x = fminf(fmaxf(x, -15.f), 15.f);
    float e = __expf(2.f * x);
    return (e - 1.f) / (e + 1.f);
}

// Zero h0 and flag words with sc1 stores (land at the chip-coherent MALL
// point where the main kernel's sc1 loads read).
__global__ __launch_bounds__(256) void zero_kernel(unsigned short* hbuf, int* cnt)
{
    const int tid = threadIdx.x, wg = blockIdx.x;
    u32x4 z = {0, 0, 0, 0};
    char* base = (char*)hbuf + ((wg * 256 + tid) * 32);   // 64*256*32B = 512 KiB
    asm volatile("global_store_dwordx4 %0, %1, off sc1" :: "v"(base), "v"(z) : "memory");
    asm volatile("global_store_dwordx4 %0, %1, off offset:16 sc1" :: "v"(base), "v"(z) : "memory");
    if (wg == 0) {
        int zz = 0;
        asm volatile("global_store_dword %0, %1, off sc1" :: "v"(cnt + tid), "v"(zz) : "memory");
    }
}

// Persistent GRU kernel. WG (bg, hs): batch rows [bg*64,+64), units [hs*32,+32).
// Structure = round 7 (best measured) with G_H=16: halves the MALL h-read
// traffic (each h element re-read once per hs-slice; 16 slices instead of 32
// -> 8 MB/step instead of 16), halves flag fan-in (16 flags), doubles MFMA
// per wave (6 independent accumulator chains).
// Sync: sc1 data stores/loads (chip-coherent MALL point); per-WG flag word
// stored after vmcnt(0) drain + __syncthreads; per-wave lane-0 poll of the
// 16 group flags with plain sc1 dwordx4 loads (no RMW, no cache maintenance).
__global__ __launch_bounds__(NTHREADS, 1) void gru_kernel(
    const float* __restrict__ z_seq, const float* __restrict__ W_ih,
    const float* __restrict__ W_hh, const float* __restrict__ b_ih,
    const float* __restrict__ b_hh, const float* __restrict__ W_out,
    const float* __restrict__ b_out, float* __restrict__ out,
    unsigned short* __restrict__ hbuf, int* __restrict__ cnt)
{
    extern __shared__ unsigned short s_w[];
    const int tid = threadIdx.x;
    const int wg  = blockIdx.x;
    const int bg  = wg & 7;
    const int hs  = wg >> 3;

    // ---- stage weights in fragment-linear order (fp32 -> bf16) ----
    // Whh: i = gu*8192 + ks*512 + ln*8 + e ; gu = gate*2 + unit-tile
    for (int i = tid; i < 49152; i += NTHREADS) {
        int e = i & 7, ln = (i >> 3) & 63, ks = (i >> 9) & 15, gu = i >> 13;
        int g = gu >> 1, u = gu & 1;
        int unit = hs * UW + u * 16 + (ln & 15);
        int k = ks * 32 + (ln >> 4) * 8 + e;
        s_w[i] = f2bf(W_hh[(g * 512 + unit) * 512 + k]);
    }
    for (int i = tid; i < 12288; i += NTHREADS) {
        int e = i & 7, ln = (i >> 3) & 63, ks = (i >> 9) & 3, gu = i >> 11;
        int g = gu >> 1, u = gu & 1;
        int unit = hs * UW + u * 16 + (ln & 15);
        int k = ks * 32 + (ln >> 4) * 8 + e;
        s_w[OFF_WIH + i] = f2bf(W_ih[(g * 512 + unit) * 128 + k]);
    }
    for (int i = tid; i < 8192; i += NTHREADS) {
        int e = i & 7, ln = (i >> 3) & 63, ks = i >> 9;
        int ocol = hs * 8 + (ln & 7);           // 8 out cols, duplicated x2
        int k = ks * 32 + (ln >> 4) * 8 + e;
        s_w[OFF_WOUT + i] = f2bf(W_out[ocol * 512 + k]);
    }
    __syncthreads();

    const int lane = tid & 63;
    const int wave = tid >> 6;
    const int li   = lane & 15;       // MFMA row-of-A / col-of-B / col-of-C
    const int kq   = lane >> 4;       // k-chunk selector
    const int jg0  = hs * UW + li;    // unit tile 0
    const int jg1  = jg0 + 16;        // unit tile 1

    const float bihr0 = b_ih[jg0], bihz0 = b_ih[NH + jg0], bihn0 = b_ih[2 * NH + jg0];
    const float bihr1 = b_ih[jg1], bihz1 = b_ih[NH + jg1], bihn1 = b_ih[2 * NH + jg1];
    const float bhhr0 = b_hh[jg0], bhhz0 = b_hh[NH + jg0], bhhn0 = b_hh[2 * NH + jg0];
    const float bhhr1 = b_hh[jg1], bhhz1 = b_hh[NH + jg1], bhhn1 = b_hh[2 * NH + jg1];
    const float bo    = b_out[hs * 8 + (li & 7)];

    const int aRow = bg * BT + wave * 16 + li;        // batch row for A frags
    const int cRow = bg * BT + wave * 16 + kq * 4;    // C rows (+q)
    float hreg[8] = {0,0,0,0,0,0,0,0};                // fp32 h (2 tiles x 4)

    const unsigned short* fb  = s_w + lane * 8;           // per-lane frag base
    const unsigned short* fbI = fb + OFF_WIH;
    unsigned short* tr = s_w + OFF_TR + wave * 576;       // 16 rows x 36 shorts

    int* gflags = cnt + bg * 32;          // 16 flag ints per group (pad 128B)
    int* myFlag = gflags + hs;
    int  dead   = 0;

    // ---- prologue: input-side pre-activations for t = 0 ----
    f32x4 ir0 = {0,0,0,0}, iz0 = {0,0,0,0}, in0 = {0,0,0,0};
    f32x4 ir1 = {0,0,0,0}, iz1 = {0,0,0,0}, in1 = {0,0,0,0};
    {
        const float* zrow = z_seq + ((long)aRow * SEQL + 0) * NIN + kq * 8;
#pragma unroll
        for (int ks = 0; ks < 4; ++ks) {
            float4 z0 = *(const float4*)(zrow + ks * 32);
            float4 z1 = *(const float4*)(zrow + ks * 32 + 4);
            union { bf16x8 v; unsigned short u[8]; } az;
            az.u[0] = f2bf(z0.x); az.u[1] = f2bf(z0.y);
            az.u[2] = f2bf(z0.z); az.u[3] = f2bf(z0.w);
            az.u[4] = f2bf(z1.x); az.u[5] = f2bf(z1.y);
            az.u[6] = f2bf(z1.z); az.u[7] = f2bf(z1.w);
            ir0 = MFMA(az.v, *(const bf16x8*)(fbI + ks * 512), ir0, 0, 0, 0);
            ir1 = MFMA(az.v, *(const bf16x8*)(fbI + 2048 + ks * 512), ir1, 0, 0, 0);
            iz0 = MFMA(az.v, *(const bf16x8*)(fbI + 4096 + ks * 512), iz0, 0, 0, 0);
            iz1 = MFMA(az.v, *(const bf16x8*)(fbI + 6144 + ks * 512), iz1, 0, 0, 0);
            in0 = MFMA(az.v, *(const bf16x8*)(fbI + 8192 + ks * 512), in0, 0, 0, 0);
            in1 = MFMA(az.v, *(const bf16x8*)(fbI + 10240 + ks * 512), in1, 0, 0, 0);
        }
    }

    for (int t = 0; t <= NSTEP; ++t) {
        const unsigned short* hin  = hbuf + (t & 1) * (BATCH * NH);
        unsigned short*       hout = hbuf + ((t & 1) ^ 1) * (BATCH * NH);

        // A fragments: sc1 = agent-scope load from the MALL coherence point
        const unsigned short* hrow = hin + aRow * NH + kq * 8;
        bf16x8 a[16];
#pragma unroll
        for (int ks = 0; ks < 16; ++ks)
            asm volatile("global_load_dwordx4 %0, %1, off offset:%2 sc1"
                         : "=v"(a[ks]) : "v"(hrow), "i"(ks * 64) : "memory");
        asm volatile("s_waitcnt vmcnt(0)" ::: "memory");
        __builtin_amdgcn_sched_barrier(0);

        // decode: a[] holds h_t; y_td needs h_{SEQL+1+td} -> emit at t=SEQL+1+td
        if (t > SEQL) {
            int td = t - SEQL - 1;
            f32x4 y4 = {0, 0, 0, 0};
#pragma unroll
            for (int ks = 0; ks < 16; ++ks)
                y4 = MFMA(a[ks], *(const bf16x8*)(fb + OFF_WOUT + ks * 512), y4, 0, 0, 0);
            if (li < 8) {
#pragma unroll
                for (int q = 0; q < 4; ++q)
                    out[((long)(cRow + q) * PRED + td) * NOUT + hs * 8 + li] = y4[q] + bo;
            }
        }
        if (t == NSTEP) break;

        // hidden-side MFMA: 96 MFMA, 6 independent chains, frag-linear reads
        f32x4 hr0 = {0,0,0,0}, hz0 = {0,0,0,0}, hn0 = {0,0,0,0};
        f32x4 hr1 = {0,0,0,0}, hz1 = {0,0,0,0}, hn1 = {0,0,0,0};
#pragma unroll
        for (int ks = 0; ks < 16; ++ks) {
            hr0 = MFMA(a[ks], *(const bf16x8*)(fb + ks * 512), hr0, 0, 0, 0);
            hr1 = MFMA(a[ks], *(const bf16x8*)(fb + 8192 + ks * 512), hr1, 0, 0, 0);
            hz0 = MFMA(a[ks], *(const bf16x8*)(fb + 16384 + ks * 512), hz0, 0, 0, 0);
            hz1 = MFMA(a[ks], *(const bf16x8*)(fb + 24576 + ks * 512), hz1, 0, 0, 0);
            hn0 = MFMA(a[ks], *(const bf16x8*)(fb + 32768 + ks * 512), hn0, 0, 0, 0);
            hn1 = MFMA(a[ks], *(const bf16x8*)(fb + 40960 + ks * 512), hn1, 0, 0, 0);
        }

        // gate math -> bf16 into per-wave LDS transpose tile (row stride 36)
#pragma unroll
        for (int q = 0; q < 4; ++q) {
            float r0 = sigm(bihr0 + ir0[q] + bhhr0 + hr0[q]);
            float z0 = sigm(bihz0 + iz0[q] + bhhz0 + hz0[q]);
            float n0 = tanh_f(bihn0 + in0[q] + r0 * (bhhn0 + hn0[q]));
            float h0 = (1.f - z0) * n0 + z0 * hreg[q];
            hreg[q] = h0;
            tr[(kq * 4 + q) * 36 + li] = f2bf(h0);

            float r1 = sigm(bihr1 + ir1[q] + bhhr1 + hr1[q]);
            float z1 = sigm(bihz1 + iz1[q] + bhhz1 + hz1[q]);
            float n1 = tanh_f(bihn1 + in1[q] + r1 * (bhhn1 + hn1[q]));
            float h1 = (1.f - z1) * n1 + z1 * hreg[4 + q];
            hreg[4 + q] = h1;
            tr[(kq * 4 + q) * 36 + 16 + li] = f2bf(h1);
        }
        asm volatile("s_waitcnt lgkmcnt(0)" ::: "memory");
        __builtin_amdgcn_sched_barrier(0);

        // coalesced h store: 64 lanes x dwordx4 sc1 (16 rows x 64B)
        {
            bf16x8 hv = *(const bf16x8*)(tr + (lane >> 2) * 36 + (lane & 3) * 8);
            int grow = bg * BT + wave * 16 + (lane >> 2);
            unsigned short* hp = hout + grow * NH + hs * UW + (lane & 3) * 8;
            asm volatile("global_store_dwordx4 %0, %1, off sc1"
                         :: "v"(hp), "v"(hv) : "memory");
        }
        asm volatile("s_waitcnt vmcnt(0)" ::: "memory");
        __syncthreads();
        if (tid == 0) {
            int v = t + 1;
            asm volatile("global_store_dword %0, %1, off sc1"
                         :: "v"(myFlag), "v"(v) : "memory");
        }

        // ---- barrier shadow: input-side pre-activations for t+1 ----
        f32x4 nir0 = {0,0,0,0}, niz0 = {0,0,0,0}, nin0 = {0,0,0,0};
        f32x4 nir1 = {0,0,0,0}, niz1 = {0,0,0,0}, nin1 = {0,0,0,0};
        if (t + 1 < SEQL) {
            const float* zrow = z_seq + ((long)aRow * SEQL + (t + 1)) * NIN + kq * 8;
#pragma unroll
            for (int ks = 0; ks < 4; ++ks) {
                float4 z0 = *(const float4*)(zrow + ks * 32);
                float4 z1 = *(const float4*)(zrow + ks * 32 + 4);
                union { bf16x8 v; unsigned short u[8]; } az;
                az.u[0] = f2bf(z0.x); az.u[1] = f2bf(z0.y);
                az.u[2] = f2bf(z0.z); az.u[3] = f2bf(z0.w);
                az.u[4] = f2bf(z1.x); az.u[5] = f2bf(z1.y);
                az.u[6] = f2bf(z1.z); az.u[7] = f2bf(z1.w);
                nir0 = MFMA(az.v, *(const bf16x8*)(fbI + ks * 512), nir0, 0, 0, 0);
                nir1 = MFMA(az.v, *(const bf16x8*)(fbI + 2048 + ks * 512), nir1, 0, 0, 0);
                niz0 = MFMA(az.v, *(const bf16x8*)(fbI + 4096 + ks * 512), niz0, 0, 0, 0);
                niz1 = MFMA(az.v, *(const bf16x8*)(fbI + 6144 + ks * 512), niz1, 0, 0, 0);
                nin0 = MFMA(az.v, *(const bf16x8*)(fbI + 8192 + ks * 512), nin0, 0, 0, 0);
                nin1 = MFMA(az.v, *(const bf16x8*)(fbI + 10240 + ks * 512), nin1, 0, 0, 0);
            }
        }

        // ---- flag-vector poll: plain sc1 loads of 16 ints, min >= t+1 ----
        // "=&v" early-clobber: outputs written by first loads while %4 (the
        // pointer) is still read by later loads (round-6 crash lesson).
        const int target = t + 1;
        int bail = 0;
        if (!dead && lane == 0) {
            int patience = 4000000;
            for (;;) {
                int4 f0, f1, f2, f3;
                asm volatile(
                    "global_load_dwordx4 %0, %4, off sc1\n\t"
                    "global_load_dwordx4 %1, %4, off offset:16 sc1\n\t"
                    "global_load_dwordx4 %2, %4, off offset:32 sc1\n\t"
                    "global_load_dwordx4 %3, %4, off offset:48 sc1\n\t"
                    "s_waitcnt vmcnt(0)"
                    : "=&v"(f0), "=&v"(f1), "=&v"(f2), "=&v"(f3)
                    : "v"(gflags) : "memory");
                int m0 = min(min(min(f0.x, f0.y), min(f0.z, f0.w)),
                             min(min(f1.x, f1.y), min(f1.z, f1.w)));
                int m1 = min(min(min(f2.x, f2.y), min(f2.z, f2.w)),
                             min(min(f3.x, f3.y), min(f3.z, f3.w)));
                if (min(m0, m1) >= target) break;
                if (--patience == 0) { bail = 1; break; }
            }
        }
        dead |= __builtin_amdgcn_readfirstlane(bail);
        __builtin_amdgcn_sched_barrier(0);

        ir0 = nir0; iz0 = niz0; in0 = nin0;
        ir1 = nir1; iz1 = niz1; in1 = nin1;
    }
}

extern "C" void kernel_launch(void* const* d_in, const int* in_sizes, int n_in,
                              void* d_out, int out_size, void* d_ws, size_t ws_size,
                              hipStream_t stream)
{
    const float* z_seq = (const float*)d_in[0];
    const float* W_ih  = (const float*)d_in[1];
    const float* W_hh  = (const float*)d_in[2];
    const float* b_ih  = (const float*)d_in[3];
    const float* b_hh  = (const float*)d_in[4];
    const float* W_out = (const float*)d_in[5];
    const float* b_out = (const float*)d_in[6];
    float* out = (float*)d_out;

    unsigned short* hbuf = (unsigned short*)d_ws;                   // 2 x [512][512] bf16
    int* cnt = (int*)((char*)d_ws + (size_t)2 * BATCH * NH * 2);    // flag words

    zero_kernel<<<dim3(64), dim3(256), 0, stream>>>(hbuf, cnt);
    gru_kernel<<<dim3(NWG), dim3(NTHREADS), LDS_BYTES, stream>>>(
        z_seq, W_ih, W_hh, b_ih, b_hh, W_out, b_out, out, hbuf, cnt);
}